// Round 3
// baseline (824.774 us; speedup 1.0000x reference)
//
#include <hip/hip_runtime.h>

// Problem constants (from reference): B=128, S=1024, RNN=1024, HID=512
#define BB 128
#define SS 1024
#define RNN 1024
#define HID 512
#define MINV -100000000.0f
#define NCHUNK 8          // s-chunks per row for partial softmax / partial output
#define CHUNK 128         // S / NCHUNK

// Native clang vector type: required for __builtin_nontemporal_load
typedef float fx4 __attribute__((ext_vector_type(4)));

__device__ __forceinline__ float fast_tanh(float x) {
    // tanh(x) = 1 - 2/(exp(2x)+1); exp via v_exp_f32, rcp via v_rcp_f32.
    // Saturates correctly: x>>0 -> e=inf -> 1; x<<0 -> e=0 -> -1.
    float e = __expf(2.0f * x);
    return 1.0f - 2.0f * __builtin_amdgcn_rcpf(e + 1.0f);
}

// ---------------------------------------------------------------------------
// K1: att_h[b,d] = bias[d] + sum_k h[b,k] * W[d,k]   (h @ W^T + b)
// wave handles 4 consecutive b and 16 consecutive d; lanes cover K=1024 via
// 4x float4 each; butterfly reduce. 1024 waves = 512 blocks x 128 threads.
// ---------------------------------------------------------------------------
__global__ __launch_bounds__(128) void k1_atth(
    const float* __restrict__ h, const float* __restrict__ W,
    const float* __restrict__ bias, float* __restrict__ atth) {
    const int lane = threadIdx.x & 63;
    const int gw = blockIdx.x * 2 + (threadIdx.x >> 6);   // 0..1023
    const int b0 = (gw >> 5) * 4;                          // 0..124
    const int d0 = (gw & 31) * 16;                         // 0..496

    const fx4* h4 = (const fx4*)h;   // 256 fx4 per row
    const fx4* W4 = (const fx4*)W;   // 256 fx4 per row

    fx4 hr[4][4];
#pragma unroll
    for (int bb = 0; bb < 4; ++bb)
#pragma unroll
        for (int j = 0; j < 4; ++j)
            hr[bb][j] = h4[(b0 + bb) * 256 + j * 64 + lane];

#pragma unroll 4
    for (int dd = 0; dd < 16; ++dd) {
        const int d = d0 + dd;
        fx4 w0 = W4[d * 256 + 0 * 64 + lane];
        fx4 w1 = W4[d * 256 + 1 * 64 + lane];
        fx4 w2 = W4[d * 256 + 2 * 64 + lane];
        fx4 w3 = W4[d * 256 + 3 * 64 + lane];
        float acc[4];
#pragma unroll
        for (int bb = 0; bb < 4; ++bb) {
            fx4 t = hr[bb][0] * w0 + hr[bb][1] * w1 + hr[bb][2] * w2 + hr[bb][3] * w3;
            acc[bb] = t.x + t.y + t.z + t.w;
        }
#pragma unroll
        for (int off = 32; off; off >>= 1) {
#pragma unroll
            for (int bb = 0; bb < 4; ++bb) acc[bb] += __shfl_xor(acc[bb], off);
        }
        if (lane == 0) {
            const float bv = bias[d];
#pragma unroll
            for (int bb = 0; bb < 4; ++bb)
                atth[(b0 + bb) * HID + d] = bv + acc[bb];
        }
    }
}

// ---------------------------------------------------------------------------
// K2: scores[b,s] = mask ? MINV : b_alpha + sum_d tanh(p[b,s,d]+atth[b,d])*wa[d]
// + per-(b,chunk) partial softmax stats (max, sum exp(x-max)).
// block = (b, chunk of 128 s), 256 threads = 4 waves, wave does 32 s.
// ---------------------------------------------------------------------------
__global__ __launch_bounds__(256) void k2_scores(
    const float* __restrict__ p, const float* __restrict__ atth,
    const float* __restrict__ walpha, const float* __restrict__ balpha,
    const int* __restrict__ mask, float* __restrict__ gscores,
    float2* __restrict__ ml) {
    const int b = blockIdx.x >> 3;
    const int q = blockIdx.x & 7;
    const int tid = threadIdx.x;
    const int lane = tid & 63;
    const int w = tid >> 6;

    const fx4* p4  = (const fx4*)p;       // 128 fx4 per (b,s) row
    const fx4* ah4 = (const fx4*)atth;    // 128 fx4 per b
    const fx4* wa4 = (const fx4*)walpha;  // 128 fx4

    const fx4 ah0 = ah4[b * 128 + lane];
    const fx4 ah1 = ah4[b * 128 + 64 + lane];
    const fx4 wa0 = wa4[lane];
    const fx4 wa1 = wa4[64 + lane];
    const float balp = balpha[0];

    __shared__ float shs[CHUNK];
    __shared__ float red[4];

    const int s0 = q * CHUNK + w * 32;
#pragma unroll 4
    for (int i = 0; i < 32; ++i) {
        const int s = s0 + i;
        const int row = (b * SS + s) * 128;
        const fx4 x0 = __builtin_nontemporal_load(&p4[row + lane]);
        const fx4 x1 = __builtin_nontemporal_load(&p4[row + 64 + lane]);
        float acc =
              fast_tanh(x0.x + ah0.x) * wa0.x
            + fast_tanh(x0.y + ah0.y) * wa0.y
            + fast_tanh(x0.z + ah0.z) * wa0.z
            + fast_tanh(x0.w + ah0.w) * wa0.w
            + fast_tanh(x1.x + ah1.x) * wa1.x
            + fast_tanh(x1.y + ah1.y) * wa1.y
            + fast_tanh(x1.z + ah1.z) * wa1.z
            + fast_tanh(x1.w + ah1.w) * wa1.w;
#pragma unroll
        for (int off = 32; off; off >>= 1) acc += __shfl_xor(acc, off);
        if (lane == 0) {
            float sc = acc + balp;
            if (mask[b * SS + s]) sc = MINV;
            shs[w * 32 + i] = sc;
        }
    }
    __syncthreads();

    // partial softmax over the 128 scores of this chunk
    float sc = (tid < CHUNK) ? shs[tid] : MINV;
    float mx = sc;
#pragma unroll
    for (int off = 32; off; off >>= 1) mx = fmaxf(mx, __shfl_xor(mx, off));
    if (lane == 0) red[w] = mx;
    __syncthreads();
    const float m = fmaxf(fmaxf(red[0], red[1]), fmaxf(red[2], red[3]));
    __syncthreads();
    float e = (tid < CHUNK) ? __expf(sc - m) : 0.0f;
#pragma unroll
    for (int off = 32; off; off >>= 1) e += __shfl_xor(e, off);
    if (lane == 0) red[w] = e;
    __syncthreads();

    if (tid < CHUNK) gscores[b * SS + q * CHUNK + tid] = sc;
    if (tid == 0) {
        float l = red[0] + red[1] + red[2] + red[3];
        ml[b * NCHUNK + q] = make_float2(m, l);
    }
}

// ---------------------------------------------------------------------------
// K4: per-(b,chunk) partial weighted sum over att_feats.
// Combines the 8 (m,l) partials in-block, builds 128 weights in LDS, then
// streams att_feats rows with fully-coalesced float4 (256 thr * 16B = 4KB/row).
// ---------------------------------------------------------------------------
__global__ __launch_bounds__(256) void k4_wsum(
    const float* __restrict__ att, const float* __restrict__ gscores,
    const float2* __restrict__ ml, float* __restrict__ partial) {
    const int b = blockIdx.x >> 3;
    const int q = blockIdx.x & 7;
    const int tid = threadIdx.x;

    float m = -1.0e30f;
#pragma unroll
    for (int j = 0; j < NCHUNK; ++j) m = fmaxf(m, ml[b * NCHUNK + j].x);
    float L = 0.0f;
#pragma unroll
    for (int j = 0; j < NCHUNK; ++j) {
        float2 v = ml[b * NCHUNK + j];
        L += v.y * __expf(v.x - m);
    }
    const float rL = 1.0f / L;

    __shared__ float shw[CHUNK];
    if (tid < CHUNK)
        shw[tid] = __expf(gscores[b * SS + q * CHUNK + tid] - m) * rL;
    __syncthreads();

    const fx4* att4 = (const fx4*)att;   // 256 fx4 per (b,s) row
    fx4 acc = (fx4){0.f, 0.f, 0.f, 0.f};
    const int base = (b * SS + q * CHUNK) * 256;
#pragma unroll 8
    for (int i = 0; i < CHUNK; ++i) {
        const float wgt = shw[i];
        const fx4 v = __builtin_nontemporal_load(&att4[base + i * 256 + tid]);
        acc += wgt * v;
    }
    ((fx4*)partial)[(q * BB + b) * 256 + tid] = acc;
}

// ---------------------------------------------------------------------------
// K5: out[b,d] = sum_q partial[q][b][d]  (deterministic combine, no atomics)
// ---------------------------------------------------------------------------
__global__ __launch_bounds__(256) void k5_comb(
    const fx4* __restrict__ partial, fx4* __restrict__ out) {
    const int idx = blockIdx.x * 256 + threadIdx.x;   // 0..32767
    fx4 a = partial[idx];
#pragma unroll
    for (int j = 1; j < NCHUNK; ++j) a += partial[j * (BB * 256) + idx];
    out[idx] = a;
}

extern "C" void kernel_launch(void* const* d_in, const int* in_sizes, int n_in,
                              void* d_out, int out_size, void* d_ws, size_t ws_size,
                              hipStream_t stream) {
    const float* h    = (const float*)d_in[0];
    const float* att  = (const float*)d_in[1];
    const float* p    = (const float*)d_in[2];
    const int*   mask = (const int*)d_in[3];
    const float* W    = (const float*)d_in[4];
    const float* bias = (const float*)d_in[5];
    const float* wal  = (const float*)d_in[6];
    const float* bal  = (const float*)d_in[7];

    char* ws = (char*)d_ws;
    float*  atth    = (float*)(ws + 0);          // 128*512*4   = 256 KB
    float*  gscores = (float*)(ws + 262144);     // 128*1024*4  = 512 KB
    float2* ml      = (float2*)(ws + 786432);    // 128*8*8     = 8 KB
    float*  partial = (float*)(ws + 794624);     // 8*128*1024*4 = 4 MB

    hipLaunchKernelGGL(k1_atth,   dim3(512),  dim3(128), 0, stream, h, W, bias, atth);
    hipLaunchKernelGGL(k2_scores, dim3(BB * NCHUNK), dim3(256), 0, stream,
                       p, atth, wal, bal, mask, gscores, ml);
    hipLaunchKernelGGL(k4_wsum,   dim3(BB * NCHUNK), dim3(256), 0, stream,
                       att, gscores, ml, partial);
    hipLaunchKernelGGL(k5_comb,   dim3(128),  dim3(256), 0, stream,
                       (const fx4*)partial, (fx4*)d_out);
}